// Round 8
// baseline (4029.465 us; speedup 1.0000x reference)
//
#include <hip/hip_runtime.h>
#include <math.h>
#include <float.h>

// Decoder: 32-step greedy GRU decode. B=64, H=E=1024, L=2, V=32000, T=32.
// R4: all GEMMs via mfma_f32_16x16x32_bf16, bf16 hi/lo split (hihi+hilo+lohi).
// R5: 4-wave blocks splitting K=1024 into 4x256 slices + LDS reduce. (3.78ms)
// R6 REGRESSED: launch_bounds(,6) VGPR strangle (spills), not the 16-row tiles.
// R7: two-phase LDS reduce (neutral -> occupancy not LDS-capped).
// R8: deep A-prefetch: whole K-slice of A frags in registers up front
//     (32 s16x8 = 16KB/wave in flight vs ~0.4KB rolling). GRU -> 16-row
//     blocks (384/layer), no occupancy caps. FP order identical to R5.

#define B_ 64
#define H_ 1024
#define V_ 32000
#define T_ 32

typedef unsigned short u16;
typedef float f32x4 __attribute__((ext_vector_type(4)));
typedef short s16x8 __attribute__((ext_vector_type(8)));
#define MFMA16 __builtin_amdgcn_mfma_f32_16x16x32_bf16

// workspace byte offsets (all 256-aligned)
#define WOH_B   0UL           // out_w hi bf16 [32000][1024]  (65,536,000 B)
#define WOL_B   65536000UL    // out_w lo
#define WIHH_B  131072000UL   // w_ih hi [2][3072][1024] (12,582,912 B)
#define WIHL_B  143654912UL
#define WHHH_B  156237824UL   // w_hh hi
#define WHHL_B  168820736UL
#define XH_B    181403648UL   // x hi bf16 [64][1024] (131,072 B)
#define XL_B    181534720UL
#define HBH_B   181665792UL   // h hi bf16 [2][64][1024] (262,144 B)
#define HBL_B   181927936UL
#define HF_B    182190080UL   // h f32 [2][64][1024] (524,288 B)
#define GT_B    182714368UL   // g_t f32 [64][6144] (1,572,864 B)
#define PV_B    184287232UL   // pval [1000][64] f32
#define PI_B    184543232UL   // pidx [1000][64] i32
#define TK_B    184799232UL   // tok [64] i32

#define OUT_H_OFF 65536000L   // 64*32*32000

__device__ __forceinline__ void bf16split(float x, u16& h, u16& l) {
  unsigned u = __float_as_uint(x);
  unsigned r = u + 0x7fff + ((u >> 16) & 1);          // RTN to bf16
  h = (u16)(r >> 16);
  float hf = __uint_as_float((unsigned)h << 16);
  float rem = x - hf;                                  // exact (Sterbenz)
  unsigned u2 = __float_as_uint(rem);
  unsigned r2 = u2 + 0x7fff + ((u2 >> 16) & 1);
  l = (u16)(r2 >> 16);
}

// fp32 -> (hi,lo) bf16 arrays, grid-stride over float4s.
__global__ void k_convert(const float* __restrict__ src, u16* __restrict__ hi,
                          u16* __restrict__ lo, int n4) {
  int i = blockIdx.x * 256 + threadIdx.x;
  int stride = gridDim.x * 256;
  for (; i < n4; i += stride) {
    float4 v = ((const float4*)src)[i];
    float x[4] = {v.x, v.y, v.z, v.w};
    u16 hh[4], ll[4];
    #pragma unroll
    for (int j = 0; j < 4; ++j) bf16split(x[j], hh[j], ll[j]);
    ushort4 ho; ho.x = hh[0]; ho.y = hh[1]; ho.z = hh[2]; ho.w = hh[3];
    ushort4 lv; lv.x = ll[0]; lv.y = ll[1]; lv.z = ll[2]; lv.w = ll[3];
    ((ushort4*)hi)[i] = ho;
    ((ushort4*)lo)[i] = lv;
  }
}

__global__ void k_init(const float* __restrict__ enc_h, float* __restrict__ hf,
                       u16* __restrict__ hhi, u16* __restrict__ hlo,
                       int* __restrict__ tok) {
  int n = blockIdx.x * 256 + threadIdx.x;   // 512*256 = 131072 = 2*64*1024
  float v = enc_h[n];                       // [l][b][k] layout matches
  hf[n] = v;
  u16 h, l; bf16split(v, h, l);
  hhi[n] = h; hlo[n] = l;
  if (n < B_) tok[n] = 0;                   // START token
}

// Finalize argmax partials, gather+relu embedding, emit x bf16 hi/lo [b][k].
__global__ void k_argmax_embed(const float* __restrict__ emb,
                               const float* __restrict__ pv, const int* __restrict__ pidx,
                               int* __restrict__ tok, u16* __restrict__ xhi,
                               u16* __restrict__ xlo, int do_argmax) {
  __shared__ float sv[1024];
  __shared__ int   si[1024];
  int tid = threadIdx.x;                    // 1024 threads, 1 block
  if (do_argmax) {
    int b = tid & 63, c = tid >> 6;
    float best = -FLT_MAX; int bi = 0x7fffffff;
    for (int i = c; i < 1000; i += 16) {
      float v = pv[i * 64 + b];
      int  ix = pidx[i * 64 + b];
      if (v > best || (v == best && ix < bi)) { best = v; bi = ix; }
    }
    sv[c * 64 + b] = best; si[c * 64 + b] = bi;
    __syncthreads();
    if (tid < 64) {
      float bv = sv[tid]; int bix = si[tid];
      #pragma unroll
      for (int c2 = 1; c2 < 16; ++c2) {
        float v2 = sv[c2 * 64 + tid]; int i2 = si[c2 * 64 + tid];
        if (v2 > bv || (v2 == bv && i2 < bix)) { bv = v2; bix = i2; }
      }
      tok[tid] = bix;                       // jnp.argmax: lowest index on ties
    }
  }
  __syncthreads();
  int b = tid >> 4, tl = tid & 15;
  const float* erow = emb + (long)tok[b] * H_;
  #pragma unroll
  for (int c = 0; c < 16; ++c) {
    int e = c * 64 + tl * 4;
    float4 v = *(const float4*)(erow + e);
    float x0 = fmaxf(v.x, 0.f), x1 = fmaxf(v.y, 0.f);
    float x2 = fmaxf(v.z, 0.f), x3 = fmaxf(v.w, 0.f);
    u16 h0,h1,h2,h3,l0,l1,l2,l3;
    bf16split(x0,h0,l0); bf16split(x1,h1,l1); bf16split(x2,h2,l2); bf16split(x3,h3,l3);
    ushort4 hv; hv.x=h0; hv.y=h1; hv.z=h2; hv.w=h3;
    ushort4 lv; lv.x=l0; lv.y=l1; lv.z=l2; lv.w=l3;
    *(ushort4*)(xhi + b * 1024 + e) = hv;
    *(ushort4*)(xlo + b * 1024 + e) = lv;
  }
}

// One wave, K-slice (256 of 1024) of D[32 rows][64 batch], bf16x3.
// ALL A-frags for the slice prefetched into registers (32 s16x8, static
// indices via full unroll). MFMA chain per acc identical to R5 (ascending
// k0; hihi, hilo, lohi). Frag layout (16x16x32, verified R4):
// A: lane holds A[lane&15][(lane>>4)*8+j]; B likewise; D: D[(lane>>4)*4+r][lane&15].
__device__ __forceinline__ void gemm32x64_pf(
    const u16* __restrict__ Ahi, const u16* __restrict__ Alo,
    const u16* __restrict__ Bhi, const u16* __restrict__ Blo,
    int lane, int kbeg, f32x4 (&acc)[2][4]) {
  int l15 = lane & 15, l4 = lane >> 4;
  const u16* pah = Ahi + l15 * 1024 + l4 * 8 + kbeg;
  const u16* pal = Alo + l15 * 1024 + l4 * 8 + kbeg;
  const u16* pbh = Bhi + l15 * 1024 + l4 * 8 + kbeg;
  const u16* pbl = Blo + l15 * 1024 + l4 * 8 + kbeg;
  s16x8 ah0[8], ah1[8], al0[8], al1[8];
  #pragma unroll
  for (int c = 0; c < 8; ++c) {
    ah0[c] = *(const s16x8*)(pah + c * 32);
    ah1[c] = *(const s16x8*)(pah + 16384 + c * 32);
    al0[c] = *(const s16x8*)(pal + c * 32);
    al1[c] = *(const s16x8*)(pal + 16384 + c * 32);
  }
  #pragma unroll
  for (int c = 0; c < 8; ++c) {
    #pragma unroll
    for (int nt = 0; nt < 4; ++nt) {
      s16x8 bh = *(const s16x8*)(pbh + nt * 16384 + c * 32);
      s16x8 bl = *(const s16x8*)(pbl + nt * 16384 + c * 32);
      acc[0][nt] = MFMA16(ah0[c], bh, acc[0][nt], 0, 0, 0);
      acc[1][nt] = MFMA16(ah1[c], bh, acc[1][nt], 0, 0, 0);
      acc[0][nt] = MFMA16(ah0[c], bl, acc[0][nt], 0, 0, 0);
      acc[1][nt] = MFMA16(ah1[c], bl, acc[1][nt], 0, 0, 0);
      acc[0][nt] = MFMA16(al0[c], bh, acc[0][nt], 0, 0, 0);
      acc[1][nt] = MFMA16(al1[c], bh, acc[1][nt], 0, 0, 0);
    }
  }
}

// 16-row variant for the GRU (16 s16x8 prefetch).
__device__ __forceinline__ void gemm16x64_pf(
    const u16* __restrict__ Ahi, const u16* __restrict__ Alo,
    const u16* __restrict__ Bhi, const u16* __restrict__ Blo,
    int lane, int kbeg, f32x4 (&acc)[4]) {
  int l15 = lane & 15, l4 = lane >> 4;
  const u16* pah = Ahi + l15 * 1024 + l4 * 8 + kbeg;
  const u16* pal = Alo + l15 * 1024 + l4 * 8 + kbeg;
  const u16* pbh = Bhi + l15 * 1024 + l4 * 8 + kbeg;
  const u16* pbl = Blo + l15 * 1024 + l4 * 8 + kbeg;
  s16x8 ah[8], al[8];
  #pragma unroll
  for (int c = 0; c < 8; ++c) {
    ah[c] = *(const s16x8*)(pah + c * 32);
    al[c] = *(const s16x8*)(pal + c * 32);
  }
  #pragma unroll
  for (int c = 0; c < 8; ++c) {
    #pragma unroll
    for (int nt = 0; nt < 4; ++nt) {
      s16x8 bh = *(const s16x8*)(pbh + nt * 16384 + c * 32);
      s16x8 bl = *(const s16x8*)(pbl + nt * 16384 + c * 32);
      acc[nt] = MFMA16(ah[c], bh, acc[nt], 0, 0, 0);
      acc[nt] = MFMA16(ah[c], bl, acc[nt], 0, 0, 0);
      acc[nt] = MFMA16(al[c], bh, acc[nt], 0, 0, 0);
    }
  }
}

// GRU gate GEMM: per layer, 384 blocks of 16 rows (0..191 ih, 192..383 hh).
// 4 waves split K 4x256; LDS reduce (20KB); writes g_t[b][row] + bias.
__global__ __launch_bounds__(256) void k_gru(
    const u16* __restrict__ aih_hi, const u16* __restrict__ aih_lo,
    const u16* __restrict__ ahh_hi, const u16* __restrict__ ahh_lo,
    const float* __restrict__ bih, const float* __restrict__ bhh,
    const u16* __restrict__ xb_hi, const u16* __restrict__ xb_lo,
    const u16* __restrict__ hb_hi, const u16* __restrict__ hb_lo,
    float* __restrict__ gt) {
  __shared__ f32x4 sacc[4][64][5];          // [wave][lane][nt], pad->5 (20KB)
  int tid = threadIdx.x;
  int wave = tid >> 6, lane = tid & 63;
  int l15 = lane & 15, l4 = lane >> 4;
  int blk = blockIdx.x;
  bool ih = blk < 192;
  int row0 = (ih ? blk : blk - 192) * 16;
  const u16* Ahi = (ih ? aih_hi : ahh_hi) + (size_t)row0 * 1024;
  const u16* Alo = (ih ? aih_lo : ahh_lo) + (size_t)row0 * 1024;
  const u16* Bhi = ih ? xb_hi : hb_hi;
  const u16* Blo = ih ? xb_lo : hb_lo;
  const float* bias = (ih ? bih : bhh) + row0;
  f32x4 acc[4];
  #pragma unroll
  for (int n = 0; n < 4; ++n) acc[n] = (f32x4){0.f, 0.f, 0.f, 0.f};
  gemm16x64_pf(Ahi, Alo, Bhi, Blo, lane, wave * 256, acc);
  #pragma unroll
  for (int nt = 0; nt < 4; ++nt) sacc[wave][lane][nt] = acc[nt];
  __syncthreads();
  // wave w owns batch tile nt=w: reduce K-slices, add bias, store.
  int grow0 = (ih ? 0 : 3072) + row0;
  int b = wave * 16 + l15;
  f32x4 s = sacc[0][lane][wave];
  #pragma unroll
  for (int j = 1; j < 4; ++j) s += sacc[j][lane][wave];
  f32x4 bs = *(const f32x4*)(bias + l4 * 4);
  *(f32x4*)(gt + (size_t)b * 6144 + grow0 + l4 * 4) = s + bs;
}

// Pointwise GRU gates (torch order r,z,n); updates h f32 + bf16 hi/lo.
__global__ void k_gates(const float* __restrict__ gt, float* __restrict__ hf,
                        u16* __restrict__ hhi, u16* __restrict__ hlo) {
  int n = blockIdx.x * 256 + threadIdx.x;   // 65536 = 64*1024, [b][j]
  int b = n >> 10, j = n & 1023;
  const float* gb = gt + (size_t)b * 6144;
  float ir = gb[j], iz = gb[j + 1024], inn = gb[j + 2048];
  float hr = gb[j + 3072], hz = gb[j + 4096], hn = gb[j + 5120];
  float r = 1.f / (1.f + expf(-(ir + hr)));
  float z = 1.f / (1.f + expf(-(iz + hz)));
  float nn = tanhf(inn + r * hn);
  float ho = hf[n];
  float hv = (1.f - z) * nn + z * ho;
  hf[n] = hv;
  u16 hh, ll; bf16split(hv, hh, ll);
  hhi[n] = hh; hlo[n] = ll;
}

// Logits: 1000 blocks x 4 waves; 32 vocab rows x 64 batch; waves split K 4x256.
// Deep A-prefetch; two-phase LDS reduce (20KB); nontemporal logits + partials.
__global__ __launch_bounds__(256) void k_logits(
    const u16* __restrict__ whi, const u16* __restrict__ wlo,
    const float* __restrict__ bo, const u16* __restrict__ xhi,
    const u16* __restrict__ xlo, float* __restrict__ pv, int* __restrict__ pidx,
    float* __restrict__ dout, int t) {
  __shared__ f32x4 sacc[4][64][5];          // [wave][lane][nt], pad->5 (20KB)
  int tid = threadIdx.x;
  int wave = tid >> 6, lane = tid & 63;
  int l15 = lane & 15, l4 = lane >> 4;
  int v0 = blockIdx.x * 32;
  f32x4 acc[2][4];
  #pragma unroll
  for (int m = 0; m < 2; ++m)
    #pragma unroll
    for (int n = 0; n < 4; ++n) acc[m][n] = (f32x4){0.f, 0.f, 0.f, 0.f};
  gemm32x64_pf(whi + (size_t)v0 * 1024, wlo + (size_t)v0 * 1024,
               xhi, xlo, lane, wave * 256, acc);
  // two-phase reduce: mt=0 then mt=1 through the same 20KB buffer.
  #pragma unroll
  for (int nt = 0; nt < 4; ++nt) sacc[wave][lane][nt] = acc[0][nt];
  __syncthreads();
  f32x4 s0 = sacc[0][lane][wave];
  #pragma unroll
  for (int j = 1; j < 4; ++j) s0 += sacc[j][lane][wave];
  __syncthreads();
  #pragma unroll
  for (int nt = 0; nt < 4; ++nt) sacc[wave][lane][nt] = acc[1][nt];
  __syncthreads();
  f32x4 s1 = sacc[0][lane][wave];
  #pragma unroll
  for (int j = 1; j < 4; ++j) s1 += sacc[j][lane][wave];
  // wave w owns batch tile nt=w: add bias, store, argmax partial.
  long b = wave * 16 + l15;
  f32x4 out0 = s0 + *(const f32x4*)(bo + v0 + l4 * 4);
  f32x4 out1 = s1 + *(const f32x4*)(bo + v0 + 16 + l4 * 4);
  float* addr = dout + b * (T_ * (long)V_) + (long)t * V_ + v0 + l4 * 4;
  __builtin_nontemporal_store(out0, (f32x4*)addr);
  __builtin_nontemporal_store(out1, (f32x4*)(addr + 16));
  float bv = -FLT_MAX; int bi = 0;
  #pragma unroll
  for (int r = 0; r < 4; ++r) {             // mt=0 then mt=1: ascending idx
    float v = out0[r];
    if (v > bv) { bv = v; bi = v0 + l4 * 4 + r; }
  }
  #pragma unroll
  for (int r = 0; r < 4; ++r) {
    float v = out1[r];
    if (v > bv) { bv = v; bi = v0 + 16 + l4 * 4 + r; }
  }
  #pragma unroll
  for (int off = 16; off < 64; off <<= 1) {   // combine l4 groups (rows)
    float ov = __shfl_xor(bv, off, 64);
    int   oi = __shfl_xor(bi, off, 64);
    if (ov > bv || (ov == bv && oi < bi)) { bv = ov; bi = oi; }
  }
  if (l4 == 0) {
    pv[blockIdx.x * 64 + wave * 16 + l15] = bv;
    pidx[blockIdx.x * 64 + wave * 16 + l15] = bi;
  }
}

__global__ void k_final(const float* __restrict__ hf, float* __restrict__ dout) {
  int n = blockIdx.x * 256 + threadIdx.x;   // 131072; hf layout == out layout
  dout[OUT_H_OFF + n] = hf[n];
}

extern "C" void kernel_launch(void* const* d_in, const int* in_sizes, int n_in,
                              void* d_out, int out_size, void* d_ws, size_t ws_size,
                              hipStream_t stream) {
  const float* enc_h = (const float*)d_in[1];
  const float* emb   = (const float*)d_in[2];
  const float* w_ih  = (const float*)d_in[3];
  const float* w_hh  = (const float*)d_in[4];
  const float* b_ih  = (const float*)d_in[5];
  const float* b_hh  = (const float*)d_in[6];
  const float* out_w = (const float*)d_in[7];
  const float* out_b = (const float*)d_in[8];
  float* out = (float*)d_out;
  char* wsb = (char*)d_ws;

  u16* woh  = (u16*)(wsb + WOH_B);
  u16* wol  = (u16*)(wsb + WOL_B);
  u16* wihh = (u16*)(wsb + WIHH_B);
  u16* wihl = (u16*)(wsb + WIHL_B);
  u16* whhh = (u16*)(wsb + WHHH_B);
  u16* whhl = (u16*)(wsb + WHHL_B);
  u16* xh   = (u16*)(wsb + XH_B);
  u16* xl   = (u16*)(wsb + XL_B);
  u16* hbh  = (u16*)(wsb + HBH_B);
  u16* hbl  = (u16*)(wsb + HBL_B);
  float* hf = (float*)(wsb + HF_B);
  float* gt = (float*)(wsb + GT_B);
  float* pv = (float*)(wsb + PV_B);
  int* pidx = (int*)(wsb + PI_B);
  int* tok  = (int*)(wsb + TK_B);

  k_convert<<<4096, 256, 0, stream>>>(out_w, woh, wol, 8192000);
  k_convert<<<2048, 256, 0, stream>>>(w_ih, wihh, wihl, 1572864);
  k_convert<<<2048, 256, 0, stream>>>(w_hh, whhh, whhl, 1572864);
  k_init<<<512, 256, 0, stream>>>(enc_h, hf, hbh, hbl, tok);

  for (int t = 0; t < T_; ++t) {
    k_argmax_embed<<<1, 1024, 0, stream>>>(emb, pv, pidx, tok, xh, xl, t > 0);
    for (int l = 0; l < 2; ++l) {
      const u16* bxh = (l == 0) ? xh : hbh;   // layer 1 input = h[0]
      const u16* bxl = (l == 0) ? xl : hbl;
      k_gru<<<384, 256, 0, stream>>>(wihh + (size_t)l * 3145728, wihl + (size_t)l * 3145728,
                                     whhh + (size_t)l * 3145728, whhl + (size_t)l * 3145728,
                                     b_ih + l * 3072, b_hh + l * 3072,
                                     bxh, bxl, hbh + l * 65536, hbl + l * 65536, gt);
      k_gates<<<256, 256, 0, stream>>>(gt, hf + l * 65536, hbh + l * 65536, hbl + l * 65536);
    }
    k_logits<<<1000, 256, 0, stream>>>(woh, wol, out_b, hbh + 65536, hbl + 65536,
                                       pv, pidx, out, t);
  }
  k_final<<<512, 256, 0, stream>>>(hf, out);
}

// Round 9
// 4001.443 us; speedup vs baseline: 1.0070x; 1.0070x over previous
//
#include <hip/hip_runtime.h>
#include <math.h>
#include <float.h>

// Decoder: 32-step greedy GRU decode. B=64, H=E=1024, L=2, V=32000, T=32.
// R4: GEMMs via mfma_f32_16x16x32_bf16, bf16 hi/lo split (hihi+hilo+lohi).
// R5: 4-wave K-split + LDS reduce (3.78ms). R6/R8 REGRESSED (VGPR-占 occupancy).
// R9: global_load_lds staging: 8-wave blocks, K split 8x128/wave, W hi/lo
//     slice staged HBM->LDS via async 16B queue (no VGPR cost, 128KB in
//     flight per CU). B prefetched to regs pre-barrier. Conflict-free LDS
//     reduce. Logits 1000 blks x 512thr; GRU 192 blks x 512thr.

#define B_ 64
#define H_ 1024
#define V_ 32000
#define T_ 32

typedef unsigned short u16;
typedef float f32x4 __attribute__((ext_vector_type(4)));
typedef short s16x8 __attribute__((ext_vector_type(8)));
#define MFMA16 __builtin_amdgcn_mfma_f32_16x16x32_bf16

// workspace byte offsets (all 256-aligned)
#define WOH_B   0UL           // out_w hi bf16 [32000][1024]  (65,536,000 B)
#define WOL_B   65536000UL    // out_w lo
#define WIHH_B  131072000UL   // w_ih hi [2][3072][1024] (12,582,912 B)
#define WIHL_B  143654912UL
#define WHHH_B  156237824UL   // w_hh hi
#define WHHL_B  168820736UL
#define XH_B    181403648UL   // x hi bf16 [64][1024] (131,072 B)
#define XL_B    181534720UL
#define HBH_B   181665792UL   // h hi bf16 [2][64][1024] (262,144 B)
#define HBL_B   181927936UL
#define HF_B    182190080UL   // h f32 [2][64][1024] (524,288 B)
#define GT_B    182714368UL   // g_t f32 [64][6144] (1,572,864 B)
#define PV_B    184287232UL   // pval [1000][64] f32
#define PI_B    184543232UL   // pidx [1000][64] i32
#define TK_B    184799232UL   // tok [64] i32

#define OUT_H_OFF 65536000L   // 64*32*32000

__device__ __forceinline__ void bf16split(float x, u16& h, u16& l) {
  unsigned u = __float_as_uint(x);
  unsigned r = u + 0x7fff + ((u >> 16) & 1);          // RTN to bf16
  h = (u16)(r >> 16);
  float hf = __uint_as_float((unsigned)h << 16);
  float rem = x - hf;                                  // exact (Sterbenz)
  unsigned u2 = __float_as_uint(rem);
  unsigned r2 = u2 + 0x7fff + ((u2 >> 16) & 1);
  l = (u16)(r2 >> 16);
}

// async global(16B/lane) -> LDS (wave-uniform base + lane*16)
__device__ __forceinline__ void ld_g2l(void* lptr, const void* gptr) {
  __builtin_amdgcn_global_load_lds(
      (const __attribute__((address_space(1))) void*)gptr,
      (__attribute__((address_space(3))) void*)lptr, 16, 0, 0);
}

// fp32 -> (hi,lo) bf16 arrays, grid-stride over float4s.
__global__ void k_convert(const float* __restrict__ src, u16* __restrict__ hi,
                          u16* __restrict__ lo, int n4) {
  int i = blockIdx.x * 256 + threadIdx.x;
  int stride = gridDim.x * 256;
  for (; i < n4; i += stride) {
    float4 v = ((const float4*)src)[i];
    float x[4] = {v.x, v.y, v.z, v.w};
    u16 hh[4], ll[4];
    #pragma unroll
    for (int j = 0; j < 4; ++j) bf16split(x[j], hh[j], ll[j]);
    ushort4 ho; ho.x = hh[0]; ho.y = hh[1]; ho.z = hh[2]; ho.w = hh[3];
    ushort4 lv; lv.x = ll[0]; lv.y = ll[1]; lv.z = ll[2]; lv.w = ll[3];
    ((ushort4*)hi)[i] = ho;
    ((ushort4*)lo)[i] = lv;
  }
}

__global__ void k_init(const float* __restrict__ enc_h, float* __restrict__ hf,
                       u16* __restrict__ hhi, u16* __restrict__ hlo,
                       int* __restrict__ tok) {
  int n = blockIdx.x * 256 + threadIdx.x;   // 512*256 = 131072 = 2*64*1024
  float v = enc_h[n];                       // [l][b][k] layout matches
  hf[n] = v;
  u16 h, l; bf16split(v, h, l);
  hhi[n] = h; hlo[n] = l;
  if (n < B_) tok[n] = 0;                   // START token
}

// Finalize argmax partials, gather+relu embedding, emit x bf16 hi/lo [b][k].
__global__ void k_argmax_embed(const float* __restrict__ emb,
                               const float* __restrict__ pv, const int* __restrict__ pidx,
                               int* __restrict__ tok, u16* __restrict__ xhi,
                               u16* __restrict__ xlo, int do_argmax) {
  __shared__ float sv[1024];
  __shared__ int   si[1024];
  int tid = threadIdx.x;                    // 1024 threads, 1 block
  if (do_argmax) {
    int b = tid & 63, c = tid >> 6;
    float best = -FLT_MAX; int bi = 0x7fffffff;
    #pragma unroll 4
    for (int i = c; i < 1000; i += 16) {
      float v = pv[i * 64 + b];
      int  ix = pidx[i * 64 + b];
      if (v > best || (v == best && ix < bi)) { best = v; bi = ix; }
    }
    sv[c * 64 + b] = best; si[c * 64 + b] = bi;
    __syncthreads();
    if (tid < 64) {
      float bv = sv[tid]; int bix = si[tid];
      #pragma unroll
      for (int c2 = 1; c2 < 16; ++c2) {
        float v2 = sv[c2 * 64 + tid]; int i2 = si[c2 * 64 + tid];
        if (v2 > bv || (v2 == bv && i2 < bix)) { bv = v2; bix = i2; }
      }
      tok[tid] = bix;                       // jnp.argmax: lowest index on ties
    }
  }
  __syncthreads();
  int b = tid >> 4, tl = tid & 15;
  const float* erow = emb + (long)tok[b] * H_;
  #pragma unroll
  for (int c = 0; c < 16; ++c) {
    int e = c * 64 + tl * 4;
    float4 v = *(const float4*)(erow + e);
    float x0 = fmaxf(v.x, 0.f), x1 = fmaxf(v.y, 0.f);
    float x2 = fmaxf(v.z, 0.f), x3 = fmaxf(v.w, 0.f);
    u16 h0,h1,h2,h3,l0,l1,l2,l3;
    bf16split(x0,h0,l0); bf16split(x1,h1,l1); bf16split(x2,h2,l2); bf16split(x3,h3,l3);
    ushort4 hv; hv.x=h0; hv.y=h1; hv.z=h2; hv.w=h3;
    ushort4 lv; lv.x=l0; lv.y=l1; lv.z=l2; lv.w=l3;
    *(ushort4*)(xhi + b * 1024 + e) = hv;
    *(ushort4*)(xlo + b * 1024 + e) = lv;
  }
}

// Shared core: wave stages its [32 rows][128 k] hi/lo W-slice into LDS via
// global_load_lds, prefetches B frags (x/h, L2-hot) into regs, then MFMA
// D[32][64] partial for its K-slice. Frag layout (16x16x32, verified R4):
// A: lane holds A[lane&15][(lane>>4)*8+j]; B likewise; D: D[(lane>>4)*4+r][lane&15].
// Per-acc chain: ascending chunk; hihi(m0) hihi(m1) hilo lohi — same as R5.
__device__ __forceinline__ void stage_gemm32x64(
    const u16* __restrict__ Ahi, const u16* __restrict__ Alo,  // +row0*1024+wave*128
    const u16* __restrict__ Bhi, const u16* __restrict__ Blo,  // base (x/h)
    char* wslice, int wave, int lane, f32x4 (&acc)[2][4]) {
  int l15 = lane & 15, l4 = lane >> 4;
  // B prefetch (32 x s16x8 from L2)
  const u16* pbh = Bhi + l15 * 1024 + l4 * 8 + wave * 128;
  const u16* pbl = Blo + l15 * 1024 + l4 * 8 + wave * 128;
  s16x8 bh[4][4], bl[4][4];
  #pragma unroll
  for (int c = 0; c < 4; ++c)
    #pragma unroll
    for (int nt = 0; nt < 4; ++nt) {
      bh[c][nt] = *(const s16x8*)(pbh + nt * 16384 + c * 32);
      bl[c][nt] = *(const s16x8*)(pbl + nt * 16384 + c * 32);
    }
  // A stage: 8 issues hi + 8 lo; issue i covers rows [i*4, i*4+4) of the slice
  // (lane j -> row i*4+(j>>4), k-bytes (j&15)*16  ==  linear dest i*1024+j*16).
  {
    int row = (lane >> 4);
    int kof = (lane & 15) * 8;
    #pragma unroll
    for (int i = 0; i < 8; ++i) {
      ld_g2l(wslice + i * 1024,        Ahi + (size_t)(i * 4 + row) * 1024 + kof);
      ld_g2l(wslice + 8192 + i * 1024, Alo + (size_t)(i * 4 + row) * 1024 + kof);
    }
  }
  __syncthreads();   // drains vmcnt (stages + B) before anyone reads LDS
  #pragma unroll
  for (int c = 0; c < 4; ++c) {
    s16x8 ah0 = *(const s16x8*)(wslice + l15 * 256 + c * 64 + l4 * 16);
    s16x8 ah1 = *(const s16x8*)(wslice + (l15 + 16) * 256 + c * 64 + l4 * 16);
    s16x8 al0 = *(const s16x8*)(wslice + 8192 + l15 * 256 + c * 64 + l4 * 16);
    s16x8 al1 = *(const s16x8*)(wslice + 8192 + (l15 + 16) * 256 + c * 64 + l4 * 16);
    #pragma unroll
    for (int nt = 0; nt < 4; ++nt) {
      acc[0][nt] = MFMA16(ah0, bh[c][nt], acc[0][nt], 0, 0, 0);
      acc[1][nt] = MFMA16(ah1, bh[c][nt], acc[1][nt], 0, 0, 0);
      acc[0][nt] = MFMA16(ah0, bl[c][nt], acc[0][nt], 0, 0, 0);
      acc[1][nt] = MFMA16(ah1, bl[c][nt], acc[1][nt], 0, 0, 0);
      acc[0][nt] = MFMA16(al0, bh[c][nt], acc[0][nt], 0, 0, 0);
      acc[1][nt] = MFMA16(al1, bh[c][nt], acc[1][nt], 0, 0, 0);
    }
  }
}

// GRU gate GEMM: 192 blocks (0..95 ih-rows vs x, 96..191 hh-rows vs h),
// 8 waves K-split 8x128, staged A; reduce; writes g_t[b][row] + bias.
__global__ __launch_bounds__(512) void k_gru(
    const u16* __restrict__ aih_hi, const u16* __restrict__ aih_lo,
    const u16* __restrict__ ahh_hi, const u16* __restrict__ ahh_lo,
    const float* __restrict__ bih, const float* __restrict__ bhh,
    const u16* __restrict__ xb_hi, const u16* __restrict__ xb_lo,
    const u16* __restrict__ hb_hi, const u16* __restrict__ hb_lo,
    float* __restrict__ gt) {
  __shared__ __align__(16) char lds[131072];   // 8 x 16KB slices; reused for reduce
  int tid = threadIdx.x;
  int wave = tid >> 6, lane = tid & 63;
  int l15 = lane & 15, l4 = lane >> 4;
  int blk = blockIdx.x;
  bool ih = blk < 96;
  int row0 = (ih ? blk : blk - 96) * 32;
  const u16* Ahi = (ih ? aih_hi : ahh_hi) + (size_t)row0 * 1024 + wave * 128;
  const u16* Alo = (ih ? aih_lo : ahh_lo) + (size_t)row0 * 1024 + wave * 128;
  const u16* Bhi = ih ? xb_hi : hb_hi;
  const u16* Blo = ih ? xb_lo : hb_lo;
  const float* bias = (ih ? bih : bhh) + row0;
  f32x4 acc[2][4];
  #pragma unroll
  for (int m = 0; m < 2; ++m)
    #pragma unroll
    for (int n = 0; n < 4; ++n) acc[m][n] = (f32x4){0.f, 0.f, 0.f, 0.f};
  stage_gemm32x64(Ahi, Alo, Bhi, Blo, lds + wave * 16384, wave, lane, acc);
  __syncthreads();                              // all waves done with slices
  f32x4* sa = (f32x4*)lds;                      // sa[e][j*64+lane], e=mt*4+nt (64KB)
  #pragma unroll
  for (int mt = 0; mt < 2; ++mt)
    #pragma unroll
    for (int nt = 0; nt < 4; ++nt)
      sa[(mt * 4 + nt) * 512 + wave * 64 + lane] = acc[mt][nt];
  __syncthreads();
  if (wave < 4) {                               // wave w owns batch tile nt=w
    f32x4 s0 = sa[wave * 512 + lane];
    f32x4 s1 = sa[(4 + wave) * 512 + lane];
    #pragma unroll
    for (int j = 1; j < 8; ++j) {
      s0 += sa[wave * 512 + j * 64 + lane];
      s1 += sa[(4 + wave) * 512 + j * 64 + lane];
    }
    int grow0 = (ih ? 0 : 3072) + row0;
    int b = wave * 16 + l15;
    f32x4 bs0 = *(const f32x4*)(bias + l4 * 4);
    f32x4 bs1 = *(const f32x4*)(bias + 16 + l4 * 4);
    *(f32x4*)(gt + (size_t)b * 6144 + grow0 + l4 * 4) = s0 + bs0;
    *(f32x4*)(gt + (size_t)b * 6144 + grow0 + 16 + l4 * 4) = s1 + bs1;
  }
}

// Pointwise GRU gates (torch order r,z,n); updates h f32 + bf16 hi/lo.
__global__ void k_gates(const float* __restrict__ gt, float* __restrict__ hf,
                        u16* __restrict__ hhi, u16* __restrict__ hlo) {
  int n = blockIdx.x * 256 + threadIdx.x;   // 65536 = 64*1024, [b][j]
  int b = n >> 10, j = n & 1023;
  const float* gb = gt + (size_t)b * 6144;
  float ir = gb[j], iz = gb[j + 1024], inn = gb[j + 2048];
  float hr = gb[j + 3072], hz = gb[j + 4096], hn = gb[j + 5120];
  float r = 1.f / (1.f + expf(-(ir + hr)));
  float z = 1.f / (1.f + expf(-(iz + hz)));
  float nn = tanhf(inn + r * hn);
  float ho = hf[n];
  float hv = (1.f - z) * nn + z * ho;
  hf[n] = hv;
  u16 hh, ll; bf16split(hv, hh, ll);
  hhi[n] = hh; hlo[n] = ll;
}

// Logits: 1000 blocks x 8 waves; 32 vocab rows; K split 8x128; staged A.
// Reduce + bias + nontemporal store + argmax partials.
__global__ __launch_bounds__(512) void k_logits(
    const u16* __restrict__ whi, const u16* __restrict__ wlo,
    const float* __restrict__ bo, const u16* __restrict__ xhi,
    const u16* __restrict__ xlo, float* __restrict__ pv, int* __restrict__ pidx,
    float* __restrict__ dout, int t) {
  __shared__ __align__(16) char lds[131072];
  int tid = threadIdx.x;
  int wave = tid >> 6, lane = tid & 63;
  int l15 = lane & 15, l4 = lane >> 4;
  int v0 = blockIdx.x * 32;
  f32x4 acc[2][4];
  #pragma unroll
  for (int m = 0; m < 2; ++m)
    #pragma unroll
    for (int n = 0; n < 4; ++n) acc[m][n] = (f32x4){0.f, 0.f, 0.f, 0.f};
  stage_gemm32x64(whi + (size_t)v0 * 1024 + wave * 128,
                  wlo + (size_t)v0 * 1024 + wave * 128,
                  xhi, xlo, lds + wave * 16384, wave, lane, acc);
  __syncthreads();
  f32x4* sa = (f32x4*)lds;                      // sa[e][j*64+lane], e=mt*4+nt
  #pragma unroll
  for (int mt = 0; mt < 2; ++mt)
    #pragma unroll
    for (int nt = 0; nt < 4; ++nt)
      sa[(mt * 4 + nt) * 512 + wave * 64 + lane] = acc[mt][nt];
  __syncthreads();
  if (wave < 4) {                               // wave w owns batch tile nt=w
    f32x4 s0 = sa[wave * 512 + lane];
    f32x4 s1 = sa[(4 + wave) * 512 + lane];
    #pragma unroll
    for (int j = 1; j < 8; ++j) {
      s0 += sa[wave * 512 + j * 64 + lane];
      s1 += sa[(4 + wave) * 512 + j * 64 + lane];
    }
    long b = wave * 16 + l15;
    f32x4 out0 = s0 + *(const f32x4*)(bo + v0 + l4 * 4);
    f32x4 out1 = s1 + *(const f32x4*)(bo + v0 + 16 + l4 * 4);
    float* addr = dout + b * (T_ * (long)V_) + (long)t * V_ + v0 + l4 * 4;
    __builtin_nontemporal_store(out0, (f32x4*)addr);
    __builtin_nontemporal_store(out1, (f32x4*)(addr + 16));
    float bv = -FLT_MAX; int bi = 0;
    #pragma unroll
    for (int r = 0; r < 4; ++r) {               // mt=0 then mt=1: ascending idx
      float v = out0[r];
      if (v > bv) { bv = v; bi = v0 + l4 * 4 + r; }
    }
    #pragma unroll
    for (int r = 0; r < 4; ++r) {
      float v = out1[r];
      if (v > bv) { bv = v; bi = v0 + 16 + l4 * 4 + r; }
    }
    #pragma unroll
    for (int off = 16; off < 64; off <<= 1) {   // combine l4 groups (rows)
      float ov = __shfl_xor(bv, off, 64);
      int   oi = __shfl_xor(bi, off, 64);
      if (ov > bv || (ov == bv && oi < bi)) { bv = ov; bi = oi; }
    }
    if (l4 == 0) {
      pv[blockIdx.x * 64 + wave * 16 + l15] = bv;
      pidx[blockIdx.x * 64 + wave * 16 + l15] = bi;
    }
  }
}

__global__ void k_final(const float* __restrict__ hf, float* __restrict__ dout) {
  int n = blockIdx.x * 256 + threadIdx.x;   // 131072; hf layout == out layout
  dout[OUT_H_OFF + n] = hf[n];
}

extern "C" void kernel_launch(void* const* d_in, const int* in_sizes, int n_in,
                              void* d_out, int out_size, void* d_ws, size_t ws_size,
                              hipStream_t stream) {
  const float* enc_h = (const float*)d_in[1];
  const float* emb   = (const float*)d_in[2];
  const float* w_ih  = (const float*)d_in[3];
  const float* w_hh  = (const float*)d_in[4];
  const float* b_ih  = (const float*)d_in[5];
  const float* b_hh  = (const float*)d_in[6];
  const float* out_w = (const float*)d_in[7];
  const float* out_b = (const float*)d_in[8];
  float* out = (float*)d_out;
  char* wsb = (char*)d_ws;

  u16* woh  = (u16*)(wsb + WOH_B);
  u16* wol  = (u16*)(wsb + WOL_B);
  u16* wihh = (u16*)(wsb + WIHH_B);
  u16* wihl = (u16*)(wsb + WIHL_B);
  u16* whhh = (u16*)(wsb + WHHH_B);
  u16* whhl = (u16*)(wsb + WHHL_B);
  u16* xh   = (u16*)(wsb + XH_B);
  u16* xl   = (u16*)(wsb + XL_B);
  u16* hbh  = (u16*)(wsb + HBH_B);
  u16* hbl  = (u16*)(wsb + HBL_B);
  float* hf = (float*)(wsb + HF_B);
  float* gt = (float*)(wsb + GT_B);
  float* pv = (float*)(wsb + PV_B);
  int* pidx = (int*)(wsb + PI_B);
  int* tok  = (int*)(wsb + TK_B);

  k_convert<<<4096, 256, 0, stream>>>(out_w, woh, wol, 8192000);
  k_convert<<<2048, 256, 0, stream>>>(w_ih, wihh, wihl, 1572864);
  k_convert<<<2048, 256, 0, stream>>>(w_hh, whhh, whhl, 1572864);
  k_init<<<512, 256, 0, stream>>>(enc_h, hf, hbh, hbl, tok);

  for (int t = 0; t < T_; ++t) {
    k_argmax_embed<<<1, 1024, 0, stream>>>(emb, pv, pidx, tok, xh, xl, t > 0);
    for (int l = 0; l < 2; ++l) {
      const u16* bxh = (l == 0) ? xh : hbh;   // layer 1 input = h[0]
      const u16* bxl = (l == 0) ? xl : hbl;
      k_gru<<<192, 512, 0, stream>>>(wihh + (size_t)l * 3145728, wihl + (size_t)l * 3145728,
                                     whhh + (size_t)l * 3145728, whhl + (size_t)l * 3145728,
                                     b_ih + l * 3072, b_hh + l * 3072,
                                     bxh, bxl, hbh + l * 65536, hbl + l * 65536, gt);
      k_gates<<<256, 256, 0, stream>>>(gt, hf + l * 65536, hbh + l * 65536, hbl + l * 65536);
    }
    k_logits<<<1000, 512, 0, stream>>>(woh, wol, out_b, hbh + 65536, hbl + 65536,
                                       pv, pidx, out, t);
  }
  k_final<<<512, 256, 0, stream>>>(hf, out);
}